// Round 8
// baseline (233.898 us; speedup 1.0000x reference)
//
#include <hip/hip_runtime.h>
#include <cstddef>

#define B_ 4
#define NQ_ 512
#define N_ 256
#define D_ 768
#define H_ 6
#define DH_ 128
#define G_ 64
#define R_ 64
#define MID_ 4096
#define EPS_ 1e-5f
#define SCALE_ 0.29730177875068026f  // 128^-0.25

typedef short bf16x8 __attribute__((ext_vector_type(8)));
typedef short short4v __attribute__((ext_vector_type(4)));
typedef float f32x4 __attribute__((ext_vector_type(4)));

__device__ __forceinline__ float b2f(short s) {
  union { float f; unsigned u; } c; c.u = ((unsigned)(unsigned short)s) << 16; return c.f;
}
__device__ __forceinline__ short f2b(float f) {
  union { float f; unsigned u; } c; c.f = f;
  unsigned r = c.u + 0x7FFFu + ((c.u >> 16) & 1u);
  return (short)(r >> 16);
}

#define AS1(p) ((const __attribute__((address_space(1))) unsigned int*)(p))
#define AS3(p) ((__attribute__((address_space(3))) unsigned int*)(p))

// ---------------- merged prep: casts (x, ctx, Wc) + vectorized transpose-casts (Wq,Wk,Wout,Wv1) ----
__global__ __launch_bounds__(256) void prep_kernel(
    const float* __restrict__ x, short* __restrict__ xb,
    const float* __restrict__ ctx, short* __restrict__ cb,
    const float* __restrict__ Wc, short* __restrict__ Wcb,
    const float* __restrict__ Wq, short* __restrict__ WqT,
    const float* __restrict__ Wk, short* __restrict__ WkT,
    const float* __restrict__ Wout, short* __restrict__ WoutT,
    const float* __restrict__ Wv1, short* __restrict__ Wv1T) {
  __shared__ float tile[64 * 65];
  int bid = blockIdx.x, t = threadIdx.x;
  if (bid < 2688) {  // plain cast, 8 elems/thread
    const float* src; short* dst; size_t i;
    if (bid < 768)       { src = x;   dst = xb;  i = ((size_t)bid * 256 + t) * 8; }
    else if (bid < 1152) { src = ctx; dst = cb;  i = ((size_t)(bid - 768) * 256 + t) * 8; }
    else                 { src = Wc;  dst = Wcb; i = ((size_t)(bid - 1152) * 256 + t) * 8; }
    float4 a = *(const float4*)&src[i], b = *(const float4*)&src[i + 4];
    bf16x8 o = {f2b(a.x), f2b(a.y), f2b(a.z), f2b(a.w),
                f2b(b.x), f2b(b.y), f2b(b.z), f2b(b.w)};
    *(bf16x8*)&dst[i] = o;
    return;
  }
  // transpose-cast 64x64 tile: src f32 [R][C] -> dst bf16 [C][R]
  const float* src; short* dst; int R, C, o;
  if (bid < 2832)      { src = Wq;   dst = WqT;   R = 768; C = 768;  o = bid - 2688; }
  else if (bid < 2976) { src = Wk;   dst = WkT;   R = 768; C = 768;  o = bid - 2832; }
  else if (bid < 3120) { src = Wout; dst = WoutT; R = 768; C = 768;  o = bid - 2976; }
  else                 { src = Wv1;  dst = Wv1T;  R = 768; C = 4096; o = bid - 3120; }
  int nct = C >> 6;
  int tr0 = (o / nct) * 64, tc0 = (o % nct) * 64;
  int rl = t >> 4, cl = (t & 15) * 4;
#pragma unroll
  for (int i = 0; i < 4; ++i) {
    float4 v = *(const float4*)&src[(size_t)(tr0 + rl + i * 16) * C + tc0 + cl];
    float* tp = &tile[(rl + i * 16) * 65 + cl];
    tp[0] = v.x; tp[1] = v.y; tp[2] = v.z; tp[3] = v.w;
  }
  __syncthreads();
#pragma unroll
  for (int i = 0; i < 4; ++i) {
    int c = rl + i * 16;
    short4v ov = {f2b(tile[(cl + 0) * 65 + c]), f2b(tile[(cl + 1) * 65 + c]),
                  f2b(tile[(cl + 2) * 65 + c]), f2b(tile[(cl + 3) * 65 + c])};
    *(short4v*)&dst[(size_t)(tc0 + c) * R + tr0 + cl] = ov;
  }
}

// ---------------- wprep: partial M = Wc^T Wc and col-sums per (g, d-quarter), raw f32 ----------------
__global__ __launch_bounds__(256) void wprep_kernel(
    const short* __restrict__ Wcb, float* __restrict__ Msum4, float* __restrict__ wcsum4) {
  __shared__ __align__(16) float wd[16][64];
  int g = blockIdx.x >> 2, qq = blockIdx.x & 3, t = threadIdx.x;
  int r1 = t >> 2, r2b = (t & 3) * 16;
  float acc[16] = {};
  float wsum = 0.f;
  const short* base = Wcb + ((size_t)g * D_ + qq * 192) * R_;
  for (int d0 = 0; d0 < 192; d0 += 16) {
    for (int idx = t; idx < 1024; idx += 256)
      wd[idx >> 6][idx & 63] = b2f(base[(size_t)(d0 + (idx >> 6)) * R_ + (idx & 63)]);
    __syncthreads();
#pragma unroll 4
    for (int i = 0; i < 16; ++i) {
      float a = wd[i][r1];
#pragma unroll
      for (int kk = 0; kk < 16; ++kk) acc[kk] += a * wd[i][r2b + kk];
    }
    if (t < 64) {
#pragma unroll 4
      for (int i = 0; i < 16; ++i) wsum += wd[i][t];
    }
    __syncthreads();
  }
  float* mp = Msum4 + ((size_t)(qq * 64 + g)) * 4096;
#pragma unroll
  for (int kk = 0; kk < 16; ++kk) mp[r1 * 64 + r2b + kk] = acc[kk];
  if (t < 64) wcsum4[(qq * 64 + g) * 64 + t] = wsum;
}

// ---------------- 128x64 MFMA GEMM tile: C = A(MxK) @ BT(NxK), K mult of 32 ----------------
__device__ __forceinline__ void gemm64_tile(
    const short* __restrict__ A, const short* __restrict__ BT,
    float* __restrict__ C, int N, int K, int m0, int n0,
    short* As /*128*32*/, short* Bs /*64*32*/) {
  int t = threadIdx.x, w = t >> 6, l = t & 63;
  int lr = l & 15, hi = l >> 4, lk = hi * 8;
  int wr = (w >> 1) * 64, wc = (w & 1) * 32;
  f32x4 acc[4][2];
#pragma unroll
  for (int i = 0; i < 4; ++i)
#pragma unroll
    for (int j = 0; j < 2; ++j) acc[i][j] = (f32x4)0.f;
  const short* Ap = A + (size_t)(m0 + (t >> 2)) * K + (t & 3) * 8;
  const short* Bp = BT + (size_t)(n0 + (t >> 2)) * K + (t & 3) * 8;
  for (int k0 = 0; k0 < K; k0 += 32) {
    __builtin_amdgcn_global_load_lds(AS1(Ap + k0), AS3(&As[w * 512]), 16, 0, 0);
    __builtin_amdgcn_global_load_lds(AS1(Ap + (size_t)64 * K + k0), AS3(&As[2048 + w * 512]), 16, 0, 0);
    __builtin_amdgcn_global_load_lds(AS1(Bp + k0), AS3(&Bs[w * 512]), 16, 0, 0);
    __syncthreads();
    bf16x8 af[4], bfr[2];
#pragma unroll
    for (int mi = 0; mi < 4; ++mi) af[mi] = *(const bf16x8*)&As[(wr + mi * 16 + lr) * 32 + lk];
#pragma unroll
    for (int ni = 0; ni < 2; ++ni) bfr[ni] = *(const bf16x8*)&Bs[(wc + ni * 16 + lr) * 32 + lk];
#pragma unroll
    for (int mi = 0; mi < 4; ++mi)
#pragma unroll
      for (int ni = 0; ni < 2; ++ni)
        acc[mi][ni] = __builtin_amdgcn_mfma_f32_16x16x32_bf16(af[mi], bfr[ni], acc[mi][ni], 0, 0, 0);
    __syncthreads();
  }
#pragma unroll
  for (int mi = 0; mi < 4; ++mi)
#pragma unroll
    for (int ni = 0; ni < 2; ++ni)
#pragma unroll
      for (int r = 0; r < 4; ++r)
        C[(size_t)(m0 + wr + mi * 16 + hi * 4 + r) * N + n0 + wc + ni * 16 + lr] = acc[mi][ni][r];
}

__global__ __launch_bounds__(256, 2) void proj_gemm_kernel(
    const short* __restrict__ xb, const short* __restrict__ WqT, float* __restrict__ tq,
    const short* __restrict__ cb, const short* __restrict__ WkT, float* __restrict__ tk,
    const short* __restrict__ Wv1T, float* __restrict__ tv) {
  __shared__ __align__(16) short As[128 * 32];
  __shared__ __align__(16) short Bs[64 * 32];
  int bid = blockIdx.x;
  if (bid < 192)      gemm64_tile(xb, WqT, tq, 768, 768, (bid / 12) * 128, (bid % 12) * 64, As, Bs);
  else if (bid < 288) { int o = bid - 192; gemm64_tile(cb, WkT, tk, 768, 768, (o / 12) * 128, (o % 12) * 64, As, Bs); }
  else                { int o = bid - 288; gemm64_tile(cb, Wv1T, tv, 4096, 768, (o / 64) * 128, (o % 64) * 64, As, Bs); }
}

__global__ __launch_bounds__(256, 2) void out_gemm_kernel(
    const short* __restrict__ aoutb, const short* __restrict__ WoutT, float* __restrict__ C) {
  __shared__ __align__(16) short As[128 * 32];
  __shared__ __align__(16) short Bs[64 * 32];
  int bid = blockIdx.x;
  gemm64_tile(aoutb, WoutT, C, 768, 768, (bid / 12) * 128, (bid % 12) * 64, As, Bs);
}

// ---------------- merged single-pass LayerNorm (row in registers) ----------------
__global__ __launch_bounds__(256) void ln_all_kernel(
    const float* __restrict__ tq, const float* __restrict__ tk, const float* __restrict__ tv,
    const float* __restrict__ gq, const float* __restrict__ bq,
    const float* __restrict__ gk, const float* __restrict__ bk,
    const float* __restrict__ gv1, const float* __restrict__ bv1,
    short* __restrict__ qb, short* __restrict__ kb, short* __restrict__ v1b) {
  __shared__ float reds[4], redq[4];
  int row = blockIdx.x, t = threadIdx.x;
  int wv = t >> 6;
  if (row < 3072) {  // C = 768, 3 elems/thread
    const float* src; const float* gamma; const float* beta;
    if (row < 2048) { src = tq + (size_t)row * 768; gamma = gq; beta = bq; }
    else            { src = tk + (size_t)(row - 2048) * 768; gamma = gk; beta = bk; }
    float v0 = src[t], v1 = src[t + 256], v2 = src[t + 512];
    float s = v0 + v1 + v2, q2 = v0 * v0 + v1 * v1 + v2 * v2;
#pragma unroll
    for (int off = 32; off; off >>= 1) { s += __shfl_down(s, off); q2 += __shfl_down(q2, off); }
    if ((t & 63) == 0) { reds[wv] = s; redq[wv] = q2; }
    __syncthreads();
    s = reds[0] + reds[1] + reds[2] + reds[3];
    q2 = redq[0] + redq[1] + redq[2] + redq[3];
    float mu = s * (1.f / 768.f), var = q2 * (1.f / 768.f) - mu * mu;
    float rstd = rsqrtf(var + EPS_);
    float o0 = ((v0 - mu) * rstd * gamma[t] + beta[t]) * SCALE_;
    float o1 = ((v1 - mu) * rstd * gamma[t + 256] + beta[t + 256]) * SCALE_;
    float o2 = ((v2 - mu) * rstd * gamma[t + 512] + beta[t + 512]) * SCALE_;
    if (row < 2048) {
      qb[(size_t)row * 768 + t] = f2b(o0);
      qb[(size_t)row * 768 + t + 256] = f2b(o1);
      qb[(size_t)row * 768 + t + 512] = f2b(o2);
    } else {
      int rr = row - 2048, b = rr >> 8, j = rr & 255;
      int c0 = t, c1 = t + 256, c2 = t + 512;
      kb[((size_t)((b * H_ + (c0 >> 7)) * N_ + j)) * DH_ + (c0 & 127)] = f2b(o0);
      kb[((size_t)((b * H_ + (c1 >> 7)) * N_ + j)) * DH_ + (c1 & 127)] = f2b(o1);
      kb[((size_t)((b * H_ + (c2 >> 7)) * N_ + j)) * DH_ + (c2 & 127)] = f2b(o2);
    }
  } else {  // C = 4096, 16 elems/thread
    int rr = row - 3072;
    const float* src = tv + (size_t)rr * 4096;
    float vals[16];
    float s = 0.f, q2 = 0.f;
#pragma unroll
    for (int p = 0; p < 16; ++p) {
      vals[p] = src[t + p * 256];
      s += vals[p]; q2 += vals[p] * vals[p];
    }
#pragma unroll
    for (int off = 32; off; off >>= 1) { s += __shfl_down(s, off); q2 += __shfl_down(q2, off); }
    if ((t & 63) == 0) { reds[wv] = s; redq[wv] = q2; }
    __syncthreads();
    s = reds[0] + reds[1] + reds[2] + reds[3];
    q2 = redq[0] + redq[1] + redq[2] + redq[3];
    float mu = s * (1.f / 4096.f), var = q2 * (1.f / 4096.f) - mu * mu;
    float rstd = rsqrtf(var + EPS_);
#pragma unroll
    for (int p = 0; p < 16; ++p) {
      int c = t + p * 256;
      v1b[(size_t)rr * 4096 + c] = f2b((vals[p] - mu) * rstd * gv1[c] + bv1[c]);
    }
  }
}

// ---------------- attention QK^T + softmax via MFMA, no LDS ----------------
__global__ __launch_bounds__(256, 2) void attn_mfma_kernel(
    const short* __restrict__ qb, const short* __restrict__ kb, short* __restrict__ Ps) {
  int b = blockIdx.z, h = blockIdx.y, i0 = blockIdx.x * 64;
  int t = threadIdx.x, w = t >> 6, l = t & 63;
  int lr = l & 15, hi = l >> 4;
  bf16x8 af[4];
  const short* qp = qb + ((size_t)(b * NQ_ + i0 + w * 16 + lr)) * D_ + h * DH_ + hi * 8;
#pragma unroll
  for (int kk = 0; kk < 4; ++kk) af[kk] = *(const bf16x8*)(qp + kk * 32);
  f32x4 acc[16];
#pragma unroll
  for (int jf = 0; jf < 16; ++jf) acc[jf] = (f32x4)0.f;
  const short* kp = kb + ((size_t)((b * H_ + h) * N_ + lr)) * DH_ + hi * 8;
#pragma unroll
  for (int kk = 0; kk < 4; ++kk)
#pragma unroll
    for (int jf = 0; jf < 16; ++jf) {
      bf16x8 bfr = *(const bf16x8*)(kp + jf * 16 * DH_ + kk * 32);
      acc[jf] = __builtin_amdgcn_mfma_f32_16x16x32_bf16(af[kk], bfr, acc[jf], 0, 0, 0);
    }
  float mx[4], sum[4];
#pragma unroll
  for (int r = 0; r < 4; ++r) {
    mx[r] = acc[0][r];
#pragma unroll
    for (int jf = 1; jf < 16; ++jf) mx[r] = fmaxf(mx[r], acc[jf][r]);
  }
#pragma unroll
  for (int off = 1; off < 16; off <<= 1)
#pragma unroll
    for (int r = 0; r < 4; ++r) mx[r] = fmaxf(mx[r], __shfl_xor(mx[r], off));
#pragma unroll
  for (int r = 0; r < 4; ++r) sum[r] = 0.f;
#pragma unroll
  for (int jf = 0; jf < 16; ++jf)
#pragma unroll
    for (int r = 0; r < 4; ++r) {
      float p = __expf(acc[jf][r] - mx[r]);
      acc[jf][r] = p; sum[r] += p;
    }
#pragma unroll
  for (int off = 1; off < 16; off <<= 1)
#pragma unroll
    for (int r = 0; r < 4; ++r) sum[r] += __shfl_xor(sum[r], off);
  float inv[4];
#pragma unroll
  for (int r = 0; r < 4; ++r) inv[r] = 1.f / sum[r];
  short* pp = Ps + ((size_t)((b * H_ + h) * NQ_ + i0 + w * 16 + hi * 4)) * N_ + lr;
#pragma unroll
  for (int jf = 0; jf < 16; ++jf)
#pragma unroll
    for (int r = 0; r < 4; ++r)
      pp[(size_t)r * N_ + jf * 16] = f2b(acc[jf][r] * inv[r]);
}

// ---------------- fused stats+conv+LN+PV: block per (b,g), 512 thr = 8 waves ----------------
// Prologue: stats via y = V1 @ [M|wcsum] MFMA (M = WcT*Wc/768 from wprep partials, bf16),
//           u-dot + 16-lane butterfly -> mean/rstd in LDS (replaces the full-conv pass 1).
// Main: 6 d-chunks: conv (MFMA) -> LN epilogue -> Ls[d][n] bf16 (264 stride) -> PV -> out.
#define LLS 264
__global__ __launch_bounds__(512, 1) void pv_mfma_kernel(
    const short* __restrict__ v1b, const short* __restrict__ Wcb,
    const short* __restrict__ Ps, const float* __restrict__ Msum4,
    const float* __restrict__ wcsum4, const float* __restrict__ gv2,
    const float* __restrict__ bv2, short* __restrict__ aoutb) {
  __shared__ __align__(16) short V1s[256 * 72];   // 36.9KB [n][r]
  __shared__ __align__(16) short Wcs[128 * 72];   // 18.4KB [d][r]
  __shared__ __align__(16) short Ls[128 * LLS];   // 67.6KB [d][n]; prologue alias: MsB[80][72]
  __shared__ __align__(16) short As2[56 * LLS];   // 29.6KB [h*8+rr][n]
  __shared__ float mean_s[256], rstd_s[256];
  int bg = blockIdx.x, b = bg >> 6, g = bg & 63;
  int t = threadIdx.x, w = t >> 6, l = t & 63;
  int lr = l & 15, hi = l >> 4, lk = hi * 8;
  short* MsB = Ls;  // [80][72]: rows 0..63 = M/768, row 64 = wcsum/768, 65..79 junk (cols ignored)

  // stage V1 slice [256][64]
#pragma unroll
  for (int it = 0; it < 4; ++it) {
    int idx = it * 512 + t;
    int n = idx >> 3, seg = (idx & 7) * 8;
    *(bf16x8*)&V1s[n * 72 + seg] =
        *(const bf16x8*)&v1b[((size_t)(b * N_ + n)) * MID_ + g * R_ + seg];
  }
  // stage MsB (65 rows x 64): sum 4 quarter-partials, scale, cast
  for (int idx = t; idx < 65 * 64; idx += 512) {
    int rho = idx >> 6, r = idx & 63;
    float v;
    if (rho < 64)
      v = Msum4[(size_t)g * 4096 + rho * 64 + r] + Msum4[(size_t)(64 + g) * 4096 + rho * 64 + r] +
          Msum4[(size_t)(128 + g) * 4096 + rho * 64 + r] + Msum4[(size_t)(192 + g) * 4096 + rho * 64 + r];
    else
      v = wcsum4[g * 64 + r] + wcsum4[(64 + g) * 64 + r] +
          wcsum4[(128 + g) * 64 + r] + wcsum4[(192 + g) * 64 + r];
    MsB[rho * 72 + r] = f2b(v * (1.f / 768.f));
  }
  // stage P rows (48) + zero pad rows 48..55
#pragma unroll
  for (int it = 0; it < 6; ++it) {
    int idx = it * 512 + t;
    int i = idx >> 6, c4 = idx & 63;
    short4v v = *(const short4v*)&Ps[((size_t)((b * H_ + (i >> 3)) * NQ_ + (i & 7) * G_ + g)) * N_ + c4 * 4];
    *(short4v*)&As2[i * LLS + c4 * 4] = v;
  }
  for (int idx = t; idx < 528; idx += 512) {
    short4v z = {0, 0, 0, 0};
    *(short4v*)&As2[48 * LLS + idx * 4] = z;
  }
  __syncthreads();

  // ---- stats: y = V1 @ MsB, then msq = y.u, mean = y[:,64] ----
  {
    f32x4 sacc[2][5];
#pragma unroll
    for (int mi = 0; mi < 2; ++mi)
#pragma unroll
      for (int nj = 0; nj < 5; ++nj) sacc[mi][nj] = (f32x4)0.f;
#pragma unroll
    for (int k0 = 0; k0 < 64; k0 += 32) {
      bf16x8 a0 = *(const bf16x8*)&V1s[(w * 32 + lr) * 72 + k0 + lk];
      bf16x8 a1 = *(const bf16x8*)&V1s[(w * 32 + 16 + lr) * 72 + k0 + lk];
#pragma unroll
      for (int nj = 0; nj < 5; ++nj) {
        bf16x8 bfr = *(const bf16x8*)&MsB[(nj * 16 + lr) * 72 + k0 + lk];
        sacc[0][nj] = __builtin_amdgcn_mfma_f32_16x16x32_bf16(a0, bfr, sacc[0][nj], 0, 0, 0);
        sacc[1][nj] = __builtin_amdgcn_mfma_f32_16x16x32_bf16(a1, bfr, sacc[1][nj], 0, 0, 0);
      }
    }
    float pmsq[2][4], pmean[2][4];
#pragma unroll
    for (int mi = 0; mi < 2; ++mi)
#pragma unroll
      for (int j = 0; j < 4; ++j) {
        int n = w * 32 + mi * 16 + hi * 4 + j;
        float s = 0.f;
#pragma unroll
        for (int nj = 0; nj < 4; ++nj)
          s += sacc[mi][nj][j] * b2f(V1s[n * 72 + nj * 16 + lr]);
        pmsq[mi][j] = s;
        pmean[mi][j] = (lr == 0) ? sacc[mi][4][j] : 0.f;
      }
#pragma unroll
    for (int off = 1; off < 16; off <<= 1)
#pragma unroll
      for (int mi = 0; mi < 2; ++mi)
#pragma unroll
        for (int j = 0; j < 4; ++j) {
          pmsq[mi][j] += __shfl_xor(pmsq[mi][j], off);
          pmean[mi][j] += __shfl_xor(pmean[mi][j], off);
        }
    if (lr == 0) {
#pragma unroll
      for (int mi = 0; mi < 2; ++mi)
#pragma unroll
        for (int j = 0; j < 4; ++j) {
          int n = w * 32 + mi * 16 + hi * 4 + j;
          float mu = pmean[mi][j];
          float var = pmsq[mi][j] - mu * mu;
          mean_s[n] = mu;
          rstd_s[n] = rsqrtf(var + EPS_);
        }
    }
  }
  // stage Wcs chunk 0
#pragma unroll
  for (int it = 0; it < 2; ++it) {
    int e = it * 512 + t;
    int dd = e >> 3, seg = (e & 7) * 8;
    *(bf16x8*)&Wcs[dd * 72 + seg] = *(const bf16x8*)&Wcb[((size_t)(g * D_ + dd)) * R_ + seg];
  }
  __syncthreads();  // MsB dead from here; Ls free

  for (int ci = 0; ci < 6; ++ci) {
    int d0 = ci * 128;
    // ---- conv: wave w owns n in [w*32, w*32+32) x 128 d ----
    f32x4 cacc[2][8];
#pragma unroll
    for (int mi = 0; mi < 2; ++mi)
#pragma unroll
      for (int ni = 0; ni < 8; ++ni) cacc[mi][ni] = (f32x4)0.f;
#pragma unroll
    for (int k0 = 0; k0 < 64; k0 += 32) {
      bf16x8 a0 = *(const bf16x8*)&V1s[(w * 32 + lr) * 72 + k0 + lk];
      bf16x8 a1 = *(const bf16x8*)&V1s[(w * 32 + 16 + lr) * 72 + k0 + lk];
#pragma unroll
      for (int ni = 0; ni < 8; ++ni) {
        bf16x8 bfr = *(const bf16x8*)&Wcs[(ni * 16 + lr) * 72 + k0 + lk];
        cacc[0][ni] = __builtin_amdgcn_mfma_f32_16x16x32_bf16(a0, bfr, cacc[0][ni], 0, 0, 0);
        cacc[1][ni] = __builtin_amdgcn_mfma_f32_16x16x32_bf16(a1, bfr, cacc[1][ni], 0, 0, 0);
      }
    }
    // ---- LN epilogue -> Ls[d][n] (264 stride) ----
    float mn[2][4], rs[2][4];
#pragma unroll
    for (int mi = 0; mi < 2; ++mi)
#pragma unroll
      for (int r = 0; r < 4; ++r) {
        int nrow = w * 32 + mi * 16 + hi * 4 + r;
        mn[mi][r] = mean_s[nrow];
        rs[mi][r] = rstd_s[nrow];
      }
    float gc[8], bc[8];
#pragma unroll
    for (int ni = 0; ni < 8; ++ni) {
      gc[ni] = gv2[d0 + ni * 16 + lr];
      bc[ni] = bv2[d0 + ni * 16 + lr];
    }
#pragma unroll
    for (int mi = 0; mi < 2; ++mi)
#pragma unroll
      for (int ni = 0; ni < 8; ++ni) {
        f32x4 c = cacc[mi][ni];
        short4v ov = {f2b((c[0] - mn[mi][0]) * rs[mi][0] * gc[ni] + bc[ni]),
                      f2b((c[1] - mn[mi][1]) * rs[mi][1] * gc[ni] + bc[ni]),
                      f2b((c[2] - mn[mi][2]) * rs[mi][2] * gc[ni] + bc[ni]),
                      f2b((c[3] - mn[mi][3]) * rs[mi][3] * gc[ni] + bc[ni])};
        *(short4v*)&Ls[(ni * 16 + lr) * LLS + w * 32 + mi * 16 + hi * 4] = ov;
      }
    __syncthreads();  // Ls complete; Wcs free

    // ---- PV: wave w owns d-cols [w*16, w*16+16) ----
    f32x4 acc2 = (f32x4)0.f;
#pragma unroll
    for (int k0 = 0; k0 < 256; k0 += 32) {
      bf16x8 pa = *(const bf16x8*)&As2[(ci * 8 + lr) * LLS + k0 + lk];
      bf16x8 pb = *(const bf16x8*)&Ls[(w * 16 + lr) * LLS + k0 + lk];
      acc2 = __builtin_amdgcn_mfma_f32_16x16x32_bf16(pa, pb, acc2, 0, 0, 0);
    }
    // prefetch next Wcs (all conv reads of this chunk done at the Ls barrier)
    if (ci < 5) {
#pragma unroll
      for (int it = 0; it < 2; ++it) {
        int e = it * 512 + t;
        int dd = e >> 3, seg = (e & 7) * 8;
        *(bf16x8*)&Wcs[dd * 72 + seg] =
            *(const bf16x8*)&Wcb[((size_t)(g * D_ + d0 + 128 + dd)) * R_ + seg];
      }
    }
    if (hi < 2) {
      int dcol = d0 + w * 16 + lr;
#pragma unroll
      for (int r = 0; r < 4; ++r) {
        int rr = hi * 4 + r;
        aoutb[((size_t)(b * NQ_ + rr * G_ + g)) * D_ + dcol] = f2b(acc2[r]);
      }
    }
    __syncthreads();  // Wcs ready, Ls free
  }
}

// ---------------- launch ----------------
extern "C" void kernel_launch(void* const* d_in, const int* in_sizes, int n_in,
                              void* d_out, int out_size, void* d_ws, size_t ws_size,
                              hipStream_t stream) {
  const float* x       = (const float*)d_in[0];
  const float* context = (const float*)d_in[1];
  const float* Wq  = (const float*)d_in[2];
  const float* gq  = (const float*)d_in[3];
  const float* bq  = (const float*)d_in[4];
  const float* Wk  = (const float*)d_in[5];
  const float* gk  = (const float*)d_in[6];
  const float* bk  = (const float*)d_in[7];
  const float* Wv1 = (const float*)d_in[8];
  const float* gv1 = (const float*)d_in[9];
  const float* bv1 = (const float*)d_in[10];
  const float* Wc  = (const float*)d_in[11];
  const float* gv2 = (const float*)d_in[12];
  const float* bv2 = (const float*)d_in[13];
  const float* Wout = (const float*)d_in[14];
  float* out = (float*)d_out;

  char* p = (char*)d_ws;
  float* tq    = (float*)p; p += (size_t)1572864 * 4;
  float* tk    = (float*)p; p += (size_t)786432 * 4;
  float* tv    = (float*)p; p += (size_t)4194304 * 4;
  float* Msum4 = (float*)p; p += (size_t)1048576 * 4;
  float* wcsum4= (float*)p; p += (size_t)16384 * 4;
  short* xb    = (short*)p; p += (size_t)1572864 * 2;
  short* cb    = (short*)p; p += (size_t)786432 * 2;
  short* WqT   = (short*)p; p += (size_t)589824 * 2;
  short* WkT   = (short*)p; p += (size_t)589824 * 2;
  short* Wv1T  = (short*)p; p += (size_t)3145728 * 2;
  short* WoutT = (short*)p; p += (size_t)589824 * 2;
  short* Wcb   = (short*)p; p += (size_t)3145728 * 2;
  short* qb    = (short*)p; p += (size_t)1572864 * 2;
  short* kb    = (short*)p; p += (size_t)786432 * 2;
  short* v1b   = (short*)p; p += (size_t)4194304 * 2;
  short* Ps    = (short*)p; p += (size_t)3145728 * 2;
  short* aoutb = (short*)p; p += (size_t)1572864 * 2;

  dim3 blk(256);
  prep_kernel<<<3888, blk, 0, stream>>>(x, xb, context, cb, Wc, Wcb,
                                        Wq, WqT, Wk, WkT, Wout, WoutT, Wv1, Wv1T);
  wprep_kernel<<<256, blk, 0, stream>>>(Wcb, Msum4, wcsum4);
  proj_gemm_kernel<<<800, blk, 0, stream>>>(xb, WqT, tq, cb, WkT, tk, Wv1T, tv);
  ln_all_kernel<<<4096, blk, 0, stream>>>(tq, tk, tv, gq, bq, gk, bk, gv1, bv1, qb, kb, v1b);
  attn_mfma_kernel<<<dim3(8, H_, B_), blk, 0, stream>>>(qb, kb, Ps);
  pv_mfma_kernel<<<B_ * G_, dim3(512), 0, stream>>>(v1b, Wcb, Ps, Msum4, wcsum4, gv2, bv2, aoutb);
  out_gemm_kernel<<<192, blk, 0, stream>>>(aoutb, WoutT, out);
}

// Round 9
// 214.431 us; speedup vs baseline: 1.0908x; 1.0908x over previous
//
#include <hip/hip_runtime.h>
#include <cstddef>

#define B_ 4
#define NQ_ 512
#define N_ 256
#define D_ 768
#define H_ 6
#define DH_ 128
#define G_ 64
#define R_ 64
#define MID_ 4096
#define EPS_ 1e-5f
#define SCALE_ 0.29730177875068026f  // 128^-0.25

typedef short bf16x8 __attribute__((ext_vector_type(8)));
typedef short short4v __attribute__((ext_vector_type(4)));
typedef float f32x4 __attribute__((ext_vector_type(4)));

__device__ __forceinline__ float b2f(short s) {
  union { float f; unsigned u; } c; c.u = ((unsigned)(unsigned short)s) << 16; return c.f;
}
__device__ __forceinline__ short f2b(float f) {
  union { float f; unsigned u; } c; c.f = f;
  unsigned r = c.u + 0x7FFFu + ((c.u >> 16) & 1u);
  return (short)(r >> 16);
}

#define AS1(p) ((const __attribute__((address_space(1))) unsigned int*)(p))
#define AS3(p) ((__attribute__((address_space(3))) unsigned int*)(p))

// ---------------- merged prep: casts (x, ctx, Wc) + vectorized transpose-casts (Wq,Wk,Wout,Wv1) ----
__global__ __launch_bounds__(256) void prep_kernel(
    const float* __restrict__ x, short* __restrict__ xb,
    const float* __restrict__ ctx, short* __restrict__ cb,
    const float* __restrict__ Wc, short* __restrict__ Wcb,
    const float* __restrict__ Wq, short* __restrict__ WqT,
    const float* __restrict__ Wk, short* __restrict__ WkT,
    const float* __restrict__ Wout, short* __restrict__ WoutT,
    const float* __restrict__ Wv1, short* __restrict__ Wv1T) {
  __shared__ float tile[64 * 65];
  int bid = blockIdx.x, t = threadIdx.x;
  if (bid < 2688) {  // plain cast, 8 elems/thread
    const float* src; short* dst; size_t i;
    if (bid < 768)       { src = x;   dst = xb;  i = ((size_t)bid * 256 + t) * 8; }
    else if (bid < 1152) { src = ctx; dst = cb;  i = ((size_t)(bid - 768) * 256 + t) * 8; }
    else                 { src = Wc;  dst = Wcb; i = ((size_t)(bid - 1152) * 256 + t) * 8; }
    float4 a = *(const float4*)&src[i], b = *(const float4*)&src[i + 4];
    bf16x8 o = {f2b(a.x), f2b(a.y), f2b(a.z), f2b(a.w),
                f2b(b.x), f2b(b.y), f2b(b.z), f2b(b.w)};
    *(bf16x8*)&dst[i] = o;
    return;
  }
  // transpose-cast 64x64 tile: src f32 [R][C] -> dst bf16 [C][R]
  const float* src; short* dst; int R, C, o;
  if (bid < 2832)      { src = Wq;   dst = WqT;   R = 768; C = 768;  o = bid - 2688; }
  else if (bid < 2976) { src = Wk;   dst = WkT;   R = 768; C = 768;  o = bid - 2832; }
  else if (bid < 3120) { src = Wout; dst = WoutT; R = 768; C = 768;  o = bid - 2976; }
  else                 { src = Wv1;  dst = Wv1T;  R = 768; C = 4096; o = bid - 3120; }
  int nct = C >> 6;
  int tr0 = (o / nct) * 64, tc0 = (o % nct) * 64;
  int rl = t >> 4, cl = (t & 15) * 4;
#pragma unroll
  for (int i = 0; i < 4; ++i) {
    float4 v = *(const float4*)&src[(size_t)(tr0 + rl + i * 16) * C + tc0 + cl];
    float* tp = &tile[(rl + i * 16) * 65 + cl];
    tp[0] = v.x; tp[1] = v.y; tp[2] = v.z; tp[3] = v.w;
  }
  __syncthreads();
#pragma unroll
  for (int i = 0; i < 4; ++i) {
    int c = rl + i * 16;
    short4v ov = {f2b(tile[(cl + 0) * 65 + c]), f2b(tile[(cl + 1) * 65 + c]),
                  f2b(tile[(cl + 2) * 65 + c]), f2b(tile[(cl + 3) * 65 + c])};
    *(short4v*)&dst[(size_t)(tc0 + c) * R + tr0 + cl] = ov;
  }
}

// ---------------- wprep: partial M = Wc^T Wc and col-sums per (g, d-sixteenth) ----------------
// 1024 blocks (g x 16 chunks of 48 rows): 4 blocks/CU = 16 waves/CU to hide LDS latency
// (round-8: 256 blocks = 1 block/CU was latency-bound at 41 us).
__global__ __launch_bounds__(256) void wprep_kernel(
    const short* __restrict__ Wcb, float* __restrict__ Msum16, float* __restrict__ wcsum16) {
  __shared__ __align__(16) float wd[16][64];
  int g = blockIdx.x >> 4, cc = blockIdx.x & 15, t = threadIdx.x;
  int r1 = t >> 2, r2b = (t & 3) * 16;
  float acc[16] = {};
  float wsum = 0.f;
  const short* base = Wcb + ((size_t)g * D_ + cc * 48) * R_;
  for (int d0 = 0; d0 < 48; d0 += 16) {
    for (int idx = t; idx < 1024; idx += 256)
      wd[idx >> 6][idx & 63] = b2f(base[(size_t)(d0 + (idx >> 6)) * R_ + (idx & 63)]);
    __syncthreads();
#pragma unroll 4
    for (int i = 0; i < 16; ++i) {
      float a = wd[i][r1];
#pragma unroll
      for (int kk = 0; kk < 16; ++kk) acc[kk] += a * wd[i][r2b + kk];
    }
    if (t < 64) {
#pragma unroll 4
      for (int i = 0; i < 16; ++i) wsum += wd[i][t];
    }
    __syncthreads();
  }
  float* mp = Msum16 + ((size_t)(cc * 64 + g)) * 4096;
#pragma unroll
  for (int kk = 0; kk < 16; ++kk) mp[r1 * 64 + r2b + kk] = acc[kk];
  if (t < 64) wcsum16[(cc * 64 + g) * 64 + t] = wsum;
}

// ---------------- wreduce: fold 16 partials -> pv-ready bf16 MsBg[g][80*72] ----------------
// rows 0..63 = M/768, row 64 = wcsum/768, rows 65..79 zeroed (junk read by pv's nj=4 frag).
__global__ __launch_bounds__(256) void wreduce_kernel(
    const float* __restrict__ Msum16, const float* __restrict__ wcsum16,
    short* __restrict__ MsBg) {
  int g = blockIdx.x, t = threadIdx.x;
  const float inv = 1.f / 768.f;
  for (int idx = t; idx < 4096; idx += 256) {
    float s = 0.f;
#pragma unroll
    for (int c = 0; c < 16; ++c) s += Msum16[((size_t)(c * 64 + g)) * 4096 + idx];
    MsBg[(size_t)g * 5760 + (idx >> 6) * 72 + (idx & 63)] = f2b(s * inv);
  }
  if (t < 64) {
    float s = 0.f;
#pragma unroll
    for (int c = 0; c < 16; ++c) s += wcsum16[(c * 64 + g) * 64 + t];
    MsBg[(size_t)g * 5760 + 64 * 72 + t] = f2b(s * inv);
  }
  for (int idx = t; idx < 15 * 72; idx += 256)
    MsBg[(size_t)g * 5760 + 65 * 72 + idx] = 0;
}

// ---------------- 128x64 MFMA GEMM tile: C = A(MxK) @ BT(NxK), K mult of 32 ----------------
__device__ __forceinline__ void gemm64_tile(
    const short* __restrict__ A, const short* __restrict__ BT,
    float* __restrict__ C, int N, int K, int m0, int n0,
    short* As /*128*32*/, short* Bs /*64*32*/) {
  int t = threadIdx.x, w = t >> 6, l = t & 63;
  int lr = l & 15, hi = l >> 4, lk = hi * 8;
  int wr = (w >> 1) * 64, wc = (w & 1) * 32;
  f32x4 acc[4][2];
#pragma unroll
  for (int i = 0; i < 4; ++i)
#pragma unroll
    for (int j = 0; j < 2; ++j) acc[i][j] = (f32x4)0.f;
  const short* Ap = A + (size_t)(m0 + (t >> 2)) * K + (t & 3) * 8;
  const short* Bp = BT + (size_t)(n0 + (t >> 2)) * K + (t & 3) * 8;
  for (int k0 = 0; k0 < K; k0 += 32) {
    __builtin_amdgcn_global_load_lds(AS1(Ap + k0), AS3(&As[w * 512]), 16, 0, 0);
    __builtin_amdgcn_global_load_lds(AS1(Ap + (size_t)64 * K + k0), AS3(&As[2048 + w * 512]), 16, 0, 0);
    __builtin_amdgcn_global_load_lds(AS1(Bp + k0), AS3(&Bs[w * 512]), 16, 0, 0);
    __syncthreads();
    bf16x8 af[4], bfr[2];
#pragma unroll
    for (int mi = 0; mi < 4; ++mi) af[mi] = *(const bf16x8*)&As[(wr + mi * 16 + lr) * 32 + lk];
#pragma unroll
    for (int ni = 0; ni < 2; ++ni) bfr[ni] = *(const bf16x8*)&Bs[(wc + ni * 16 + lr) * 32 + lk];
#pragma unroll
    for (int mi = 0; mi < 4; ++mi)
#pragma unroll
      for (int ni = 0; ni < 2; ++ni)
        acc[mi][ni] = __builtin_amdgcn_mfma_f32_16x16x32_bf16(af[mi], bfr[ni], acc[mi][ni], 0, 0, 0);
    __syncthreads();
  }
#pragma unroll
  for (int mi = 0; mi < 4; ++mi)
#pragma unroll
    for (int ni = 0; ni < 2; ++ni)
#pragma unroll
      for (int r = 0; r < 4; ++r)
        C[(size_t)(m0 + wr + mi * 16 + hi * 4 + r) * N + n0 + wc + ni * 16 + lr] = acc[mi][ni][r];
}

__global__ __launch_bounds__(256, 2) void proj_gemm_kernel(
    const short* __restrict__ xb, const short* __restrict__ WqT, float* __restrict__ tq,
    const short* __restrict__ cb, const short* __restrict__ WkT, float* __restrict__ tk,
    const short* __restrict__ Wv1T, float* __restrict__ tv) {
  __shared__ __align__(16) short As[128 * 32];
  __shared__ __align__(16) short Bs[64 * 32];
  int bid = blockIdx.x;
  if (bid < 192)      gemm64_tile(xb, WqT, tq, 768, 768, (bid / 12) * 128, (bid % 12) * 64, As, Bs);
  else if (bid < 288) { int o = bid - 192; gemm64_tile(cb, WkT, tk, 768, 768, (o / 12) * 128, (o % 12) * 64, As, Bs); }
  else                { int o = bid - 288; gemm64_tile(cb, Wv1T, tv, 4096, 768, (o / 64) * 128, (o % 64) * 64, As, Bs); }
}

__global__ __launch_bounds__(256, 2) void out_gemm_kernel(
    const short* __restrict__ aoutb, const short* __restrict__ WoutT, float* __restrict__ C) {
  __shared__ __align__(16) short As[128 * 32];
  __shared__ __align__(16) short Bs[64 * 32];
  int bid = blockIdx.x;
  gemm64_tile(aoutb, WoutT, C, 768, 768, (bid / 12) * 128, (bid % 12) * 64, As, Bs);
}

// ---------------- merged single-pass LayerNorm (row in registers) ----------------
__global__ __launch_bounds__(256) void ln_all_kernel(
    const float* __restrict__ tq, const float* __restrict__ tk, const float* __restrict__ tv,
    const float* __restrict__ gq, const float* __restrict__ bq,
    const float* __restrict__ gk, const float* __restrict__ bk,
    const float* __restrict__ gv1, const float* __restrict__ bv1,
    short* __restrict__ qb, short* __restrict__ kb, short* __restrict__ v1b) {
  __shared__ float reds[4], redq[4];
  int row = blockIdx.x, t = threadIdx.x;
  int wv = t >> 6;
  if (row < 3072) {  // C = 768, 3 elems/thread
    const float* src; const float* gamma; const float* beta;
    if (row < 2048) { src = tq + (size_t)row * 768; gamma = gq; beta = bq; }
    else            { src = tk + (size_t)(row - 2048) * 768; gamma = gk; beta = bk; }
    float v0 = src[t], v1 = src[t + 256], v2 = src[t + 512];
    float s = v0 + v1 + v2, q2 = v0 * v0 + v1 * v1 + v2 * v2;
#pragma unroll
    for (int off = 32; off; off >>= 1) { s += __shfl_down(s, off); q2 += __shfl_down(q2, off); }
    if ((t & 63) == 0) { reds[wv] = s; redq[wv] = q2; }
    __syncthreads();
    s = reds[0] + reds[1] + reds[2] + reds[3];
    q2 = redq[0] + redq[1] + redq[2] + redq[3];
    float mu = s * (1.f / 768.f), var = q2 * (1.f / 768.f) - mu * mu;
    float rstd = rsqrtf(var + EPS_);
    float o0 = ((v0 - mu) * rstd * gamma[t] + beta[t]) * SCALE_;
    float o1 = ((v1 - mu) * rstd * gamma[t + 256] + beta[t + 256]) * SCALE_;
    float o2 = ((v2 - mu) * rstd * gamma[t + 512] + beta[t + 512]) * SCALE_;
    if (row < 2048) {
      qb[(size_t)row * 768 + t] = f2b(o0);
      qb[(size_t)row * 768 + t + 256] = f2b(o1);
      qb[(size_t)row * 768 + t + 512] = f2b(o2);
    } else {
      int rr = row - 2048, b = rr >> 8, j = rr & 255;
      int c0 = t, c1 = t + 256, c2 = t + 512;
      kb[((size_t)((b * H_ + (c0 >> 7)) * N_ + j)) * DH_ + (c0 & 127)] = f2b(o0);
      kb[((size_t)((b * H_ + (c1 >> 7)) * N_ + j)) * DH_ + (c1 & 127)] = f2b(o1);
      kb[((size_t)((b * H_ + (c2 >> 7)) * N_ + j)) * DH_ + (c2 & 127)] = f2b(o2);
    }
  } else {  // C = 4096, 16 elems/thread
    int rr = row - 3072;
    const float* src = tv + (size_t)rr * 4096;
    float vals[16];
    float s = 0.f, q2 = 0.f;
#pragma unroll
    for (int p = 0; p < 16; ++p) {
      vals[p] = src[t + p * 256];
      s += vals[p]; q2 += vals[p] * vals[p];
    }
#pragma unroll
    for (int off = 32; off; off >>= 1) { s += __shfl_down(s, off); q2 += __shfl_down(q2, off); }
    if ((t & 63) == 0) { reds[wv] = s; redq[wv] = q2; }
    __syncthreads();
    s = reds[0] + reds[1] + reds[2] + reds[3];
    q2 = redq[0] + redq[1] + redq[2] + redq[3];
    float mu = s * (1.f / 4096.f), var = q2 * (1.f / 4096.f) - mu * mu;
    float rstd = rsqrtf(var + EPS_);
#pragma unroll
    for (int p = 0; p < 16; ++p) {
      int c = t + p * 256;
      v1b[(size_t)rr * 4096 + c] = f2b((vals[p] - mu) * rstd * gv1[c] + bv1[c]);
    }
  }
}

// ---------------- attention QK^T + softmax via MFMA, no LDS ----------------
__global__ __launch_bounds__(256, 2) void attn_mfma_kernel(
    const short* __restrict__ qb, const short* __restrict__ kb, short* __restrict__ Ps) {
  int b = blockIdx.z, h = blockIdx.y, i0 = blockIdx.x * 64;
  int t = threadIdx.x, w = t >> 6, l = t & 63;
  int lr = l & 15, hi = l >> 4;
  bf16x8 af[4];
  const short* qp = qb + ((size_t)(b * NQ_ + i0 + w * 16 + lr)) * D_ + h * DH_ + hi * 8;
#pragma unroll
  for (int kk = 0; kk < 4; ++kk) af[kk] = *(const bf16x8*)(qp + kk * 32);
  f32x4 acc[16];
#pragma unroll
  for (int jf = 0; jf < 16; ++jf) acc[jf] = (f32x4)0.f;
  const short* kp = kb + ((size_t)((b * H_ + h) * N_ + lr)) * DH_ + hi * 8;
#pragma unroll
  for (int kk = 0; kk < 4; ++kk)
#pragma unroll
    for (int jf = 0; jf < 16; ++jf) {
      bf16x8 bfr = *(const bf16x8*)(kp + jf * 16 * DH_ + kk * 32);
      acc[jf] = __builtin_amdgcn_mfma_f32_16x16x32_bf16(af[kk], bfr, acc[jf], 0, 0, 0);
    }
  float mx[4], sum[4];
#pragma unroll
  for (int r = 0; r < 4; ++r) {
    mx[r] = acc[0][r];
#pragma unroll
    for (int jf = 1; jf < 16; ++jf) mx[r] = fmaxf(mx[r], acc[jf][r]);
  }
#pragma unroll
  for (int off = 1; off < 16; off <<= 1)
#pragma unroll
    for (int r = 0; r < 4; ++r) mx[r] = fmaxf(mx[r], __shfl_xor(mx[r], off));
#pragma unroll
  for (int r = 0; r < 4; ++r) sum[r] = 0.f;
#pragma unroll
  for (int jf = 0; jf < 16; ++jf)
#pragma unroll
    for (int r = 0; r < 4; ++r) {
      float p = __expf(acc[jf][r] - mx[r]);
      acc[jf][r] = p; sum[r] += p;
    }
#pragma unroll
  for (int off = 1; off < 16; off <<= 1)
#pragma unroll
    for (int r = 0; r < 4; ++r) sum[r] += __shfl_xor(sum[r], off);
  float inv[4];
#pragma unroll
  for (int r = 0; r < 4; ++r) inv[r] = 1.f / sum[r];
  short* pp = Ps + ((size_t)((b * H_ + h) * NQ_ + i0 + w * 16 + hi * 4)) * N_ + lr;
#pragma unroll
  for (int jf = 0; jf < 16; ++jf)
#pragma unroll
    for (int r = 0; r < 4; ++r)
      pp[(size_t)r * N_ + jf * 16] = f2b(acc[jf][r] * inv[r]);
}

// ---------------- fused stats+conv+LN+PV: block per (b,g), 512 thr = 8 waves ----------------
// Prologue: stats via y = V1 @ [M|wcsum] MFMA (MsBg prefolded bf16 by wreduce),
//           u-dot + 16-lane butterfly -> mean/rstd in LDS.
// Main: 6 d-chunks: conv (MFMA) -> LN epilogue -> Ls[d][n] bf16 (264 stride) -> PV -> out.
#define LLS 264
__global__ __launch_bounds__(512, 1) void pv_mfma_kernel(
    const short* __restrict__ v1b, const short* __restrict__ Wcb,
    const short* __restrict__ Ps, const short* __restrict__ MsBg,
    const float* __restrict__ gv2, const float* __restrict__ bv2,
    short* __restrict__ aoutb) {
  __shared__ __align__(16) short V1s[256 * 72];   // 36.9KB [n][r]
  __shared__ __align__(16) short Wcs[128 * 72];   // 18.4KB [d][r]
  __shared__ __align__(16) short Ls[128 * LLS];   // 67.6KB [d][n]; prologue alias: MsB[80][72]
  __shared__ __align__(16) short As2[56 * LLS];   // 29.6KB [h*8+rr][n]
  __shared__ float mean_s[256], rstd_s[256];
  int bg = blockIdx.x, b = bg >> 6, g = bg & 63;
  int t = threadIdx.x, w = t >> 6, l = t & 63;
  int lr = l & 15, hi = l >> 4, lk = hi * 8;
  short* MsB = Ls;  // [80][72]: rows 0..63 = M/768, row 64 = wcsum/768, 65..79 zero

  // stage V1 slice [256][64]
#pragma unroll
  for (int it = 0; it < 4; ++it) {
    int idx = it * 512 + t;
    int n = idx >> 3, seg = (idx & 7) * 8;
    *(bf16x8*)&V1s[n * 72 + seg] =
        *(const bf16x8*)&v1b[((size_t)(b * N_ + n)) * MID_ + g * R_ + seg];
  }
  // stage MsB: prefolded by wreduce, plain vector copy (720 x bf16x8)
  for (int e = t; e < 720; e += 512)
    *(bf16x8*)&MsB[e * 8] = *(const bf16x8*)&MsBg[(size_t)g * 5760 + e * 8];
  // stage P rows (48) + zero pad rows 48..55
#pragma unroll
  for (int it = 0; it < 6; ++it) {
    int idx = it * 512 + t;
    int i = idx >> 6, c4 = idx & 63;
    short4v v = *(const short4v*)&Ps[((size_t)((b * H_ + (i >> 3)) * NQ_ + (i & 7) * G_ + g)) * N_ + c4 * 4];
    *(short4v*)&As2[i * LLS + c4 * 4] = v;
  }
  for (int idx = t; idx < 528; idx += 512) {
    short4v z = {0, 0, 0, 0};
    *(short4v*)&As2[48 * LLS + idx * 4] = z;
  }
  __syncthreads();

  // ---- stats: y = V1 @ MsB, then msq = y.u, mean = y[:,64] ----
  {
    f32x4 sacc[2][5];
#pragma unroll
    for (int mi = 0; mi < 2; ++mi)
#pragma unroll
      for (int nj = 0; nj < 5; ++nj) sacc[mi][nj] = (f32x4)0.f;
#pragma unroll
    for (int k0 = 0; k0 < 64; k0 += 32) {
      bf16x8 a0 = *(const bf16x8*)&V1s[(w * 32 + lr) * 72 + k0 + lk];
      bf16x8 a1 = *(const bf16x8*)&V1s[(w * 32 + 16 + lr) * 72 + k0 + lk];
#pragma unroll
      for (int nj = 0; nj < 5; ++nj) {
        bf16x8 bfr = *(const bf16x8*)&MsB[(nj * 16 + lr) * 72 + k0 + lk];
        sacc[0][nj] = __builtin_amdgcn_mfma_f32_16x16x32_bf16(a0, bfr, sacc[0][nj], 0, 0, 0);
        sacc[1][nj] = __builtin_amdgcn_mfma_f32_16x16x32_bf16(a1, bfr, sacc[1][nj], 0, 0, 0);
      }
    }
    float pmsq[2][4], pmean[2][4];
#pragma unroll
    for (int mi = 0; mi < 2; ++mi)
#pragma unroll
      for (int j = 0; j < 4; ++j) {
        int n = w * 32 + mi * 16 + hi * 4 + j;
        float s = 0.f;
#pragma unroll
        for (int nj = 0; nj < 4; ++nj)
          s += sacc[mi][nj][j] * b2f(V1s[n * 72 + nj * 16 + lr]);
        pmsq[mi][j] = s;
        pmean[mi][j] = (lr == 0) ? sacc[mi][4][j] : 0.f;
      }
#pragma unroll
    for (int off = 1; off < 16; off <<= 1)
#pragma unroll
      for (int mi = 0; mi < 2; ++mi)
#pragma unroll
        for (int j = 0; j < 4; ++j) {
          pmsq[mi][j] += __shfl_xor(pmsq[mi][j], off);
          pmean[mi][j] += __shfl_xor(pmean[mi][j], off);
        }
    if (lr == 0) {
#pragma unroll
      for (int mi = 0; mi < 2; ++mi)
#pragma unroll
        for (int j = 0; j < 4; ++j) {
          int n = w * 32 + mi * 16 + hi * 4 + j;
          float mu = pmean[mi][j];
          float var = pmsq[mi][j] - mu * mu;
          mean_s[n] = mu;
          rstd_s[n] = rsqrtf(var + EPS_);
        }
    }
  }
  // stage Wcs chunk 0
#pragma unroll
  for (int it = 0; it < 2; ++it) {
    int e = it * 512 + t;
    int dd = e >> 3, seg = (e & 7) * 8;
    *(bf16x8*)&Wcs[dd * 72 + seg] = *(const bf16x8*)&Wcb[((size_t)(g * D_ + dd)) * R_ + seg];
  }
  __syncthreads();  // MsB dead from here; Ls free

  for (int ci = 0; ci < 6; ++ci) {
    int d0 = ci * 128;
    // ---- conv: wave w owns n in [w*32, w*32+32) x 128 d ----
    f32x4 cacc[2][8];
#pragma unroll
    for (int mi = 0; mi < 2; ++mi)
#pragma unroll
      for (int ni = 0; ni < 8; ++ni) cacc[mi][ni] = (f32x4)0.f;
#pragma unroll
    for (int k0 = 0; k0 < 64; k0 += 32) {
      bf16x8 a0 = *(const bf16x8*)&V1s[(w * 32 + lr) * 72 + k0 + lk];
      bf16x8 a1 = *(const bf16x8*)&V1s[(w * 32 + 16 + lr) * 72 + k0 + lk];
#pragma unroll
      for (int ni = 0; ni < 8; ++ni) {
        bf16x8 bfr = *(const bf16x8*)&Wcs[(ni * 16 + lr) * 72 + k0 + lk];
        cacc[0][ni] = __builtin_amdgcn_mfma_f32_16x16x32_bf16(a0, bfr, cacc[0][ni], 0, 0, 0);
        cacc[1][ni] = __builtin_amdgcn_mfma_f32_16x16x32_bf16(a1, bfr, cacc[1][ni], 0, 0, 0);
      }
    }
    // ---- LN epilogue -> Ls[d][n] (264 stride) ----
    float mn[2][4], rs[2][4];
#pragma unroll
    for (int mi = 0; mi < 2; ++mi)
#pragma unroll
      for (int r = 0; r < 4; ++r) {
        int nrow = w * 32 + mi * 16 + hi * 4 + r;
        mn[mi][r] = mean_s[nrow];
        rs[mi][r] = rstd_s[nrow];
      }
    float gc[8], bc[8];
#pragma unroll
    for (int ni = 0; ni < 8; ++ni) {
      gc[ni] = gv2[d0 + ni * 16 + lr];
      bc[ni] = bv2[d0 + ni * 16 + lr];
    }
#pragma unroll
    for (int mi = 0; mi < 2; ++mi)
#pragma unroll
      for (int ni = 0; ni < 8; ++ni) {
        f32x4 c = cacc[mi][ni];
        short4v ov = {f2b((c[0] - mn[mi][0]) * rs[mi][0] * gc[ni] + bc[ni]),
                      f2b((c[1] - mn[mi][1]) * rs[mi][1] * gc[ni] + bc[ni]),
                      f2b((c[2] - mn[mi][2]) * rs[mi][2] * gc[ni] + bc[ni]),
                      f2b((c[3] - mn[mi][3]) * rs[mi][3] * gc[ni] + bc[ni])};
        *(short4v*)&Ls[(ni * 16 + lr) * LLS + w * 32 + mi * 16 + hi * 4] = ov;
      }
    __syncthreads();  // Ls complete; Wcs free

    // ---- PV: wave w owns d-cols [w*16, w*16+16) ----
    f32x4 acc2 = (f32x4)0.f;
#pragma unroll
    for (int k0 = 0; k0 < 256; k0 += 32) {
      bf16x8 pa = *(const bf16x8*)&As2[(ci * 8 + lr) * LLS + k0 + lk];
      bf16x8 pb = *(const bf16x8*)&Ls[(w * 16 + lr) * LLS + k0 + lk];
      acc2 = __builtin_amdgcn_mfma_f32_16x16x32_bf16(pa, pb, acc2, 0, 0, 0);
    }
    // prefetch next Wcs (all conv reads of this chunk done at the Ls barrier)
    if (ci < 5) {
#pragma unroll
      for (int it = 0; it < 2; ++it) {
        int e = it * 512 + t;
        int dd = e >> 3, seg = (e & 7) * 8;
        *(bf16x8*)&Wcs[dd * 72 + seg] =
            *(const bf16x8*)&Wcb[((size_t)(g * D_ + d0 + 128 + dd)) * R_ + seg];
      }
    }
    if (hi < 2) {
      int dcol = d0 + w * 16 + lr;
#pragma unroll
      for (int r = 0; r < 4; ++r) {
        int rr = hi * 4 + r;
        aoutb[((size_t)(b * NQ_ + rr * G_ + g)) * D_ + dcol] = f2b(acc2[r]);
      }
    }
    __syncthreads();  // Wcs ready, Ls free
  }
}

// ---------------- launch ----------------
extern "C" void kernel_launch(void* const* d_in, const int* in_sizes, int n_in,
                              void* d_out, int out_size, void* d_ws, size_t ws_size,
                              hipStream_t stream) {
  const float* x       = (const float*)d_in[0];
  const float* context = (const float*)d_in[1];
  const float* Wq  = (const float*)d_in[2];
  const float* gq  = (const float*)d_in[3];
  const float* bq  = (const float*)d_in[4];
  const float* Wk  = (const float*)d_in[5];
  const float* gk  = (const float*)d_in[6];
  const float* bk  = (const float*)d_in[7];
  const float* Wv1 = (const float*)d_in[8];
  const float* gv1 = (const float*)d_in[9];
  const float* bv1 = (const float*)d_in[10];
  const float* Wc  = (const float*)d_in[11];
  const float* gv2 = (const float*)d_in[12];
  const float* bv2 = (const float*)d_in[13];
  const float* Wout = (const float*)d_in[14];
  float* out = (float*)d_out;

  char* p = (char*)d_ws;
  float* tq     = (float*)p; p += (size_t)1572864 * 4;
  float* tk     = (float*)p; p += (size_t)786432 * 4;
  float* tv     = (float*)p; p += (size_t)4194304 * 4;
  float* Msum16 = (float*)p; p += (size_t)4194304 * 4;   // 1024 x 4096
  float* wcsum16= (float*)p; p += (size_t)65536 * 4;     // 1024 x 64
  short* MsBg   = (short*)p; p += (size_t)368640 * 2;    // 64 x 5760
  short* xb     = (short*)p; p += (size_t)1572864 * 2;
  short* cb     = (short*)p; p += (size_t)786432 * 2;
  short* WqT    = (short*)p; p += (size_t)589824 * 2;
  short* WkT    = (short*)p; p += (size_t)589824 * 2;
  short* Wv1T   = (short*)p; p += (size_t)3145728 * 2;
  short* WoutT  = (short*)p; p += (size_t)589824 * 2;
  short* Wcb    = (short*)p; p += (size_t)3145728 * 2;
  short* qb     = (short*)p; p += (size_t)1572864 * 2;
  short* kb     = (short*)p; p += (size_t)786432 * 2;
  short* v1b    = (short*)p; p += (size_t)4194304 * 2;
  short* Ps     = (short*)p; p += (size_t)3145728 * 2;
  short* aoutb  = (short*)p; p += (size_t)1572864 * 2;

  dim3 blk(256);
  prep_kernel<<<3888, blk, 0, stream>>>(x, xb, context, cb, Wc, Wcb,
                                        Wq, WqT, Wk, WkT, Wout, WoutT, Wv1, Wv1T);
  wprep_kernel<<<1024, blk, 0, stream>>>(Wcb, Msum16, wcsum16);
  wreduce_kernel<<<64, blk, 0, stream>>>(Msum16, wcsum16, MsBg);
  proj_gemm_kernel<<<800, blk, 0, stream>>>(xb, WqT, tq, cb, WkT, tk, Wv1T, tv);
  ln_all_kernel<<<4096, blk, 0, stream>>>(tq, tk, tv, gq, bq, gk, bk, gv1, bv1, qb, kb, v1b);
  attn_mfma_kernel<<<dim3(8, H_, B_), blk, 0, stream>>>(qb, kb, Ps);
  pv_mfma_kernel<<<B_ * G_, dim3(512), 0, stream>>>(v1b, Wcb, Ps, MsBg, gv2, bv2, aoutb);
  out_gemm_kernel<<<192, blk, 0, stream>>>(aoutb, WoutT, out);
}